// Round 5
// baseline (430.828 us; speedup 1.0000x reference)
//
#include <hip/hip_runtime.h>
#include <hip/hip_bf16.h>
#include <stdint.h>

// Problem constants (FC_Caps): B=32, I=1024, O=64, D_out=32, D_in=16
#define B_   32
#define I_   1024
#define O_   64
#define D_   32
#define N_   16
#define OD_  2048   // O_*D_
#define NCH0 64     // iter-0 chunk count (16 i per chunk) — keeps ws at proven 140.25 MiB

// ---------- bf16 helpers (bit-exact RNE pack, shift unpack) ----------
__device__ __forceinline__ uint32_t f2bf1(float f) {
  uint32_t u = __float_as_uint(f);
  return (u + 0x7fffu + ((u >> 16) & 1u)) >> 16;
}
__device__ __forceinline__ uint32_t pack2(float a, float b) {
  return f2bf1(a) | (f2bf1(b) << 16);
}
__device__ __forceinline__ float bflo(uint32_t v) { return __uint_as_float(v << 16); }
__device__ __forceinline__ float bfhi(uint32_t v) { return __uint_as_float(v & 0xffff0000u); }
__device__ __forceinline__ void unpack8(uint4 r, float* u) {
  u[0] = bflo(r.x); u[1] = bfhi(r.x);
  u[2] = bflo(r.y); u[3] = bfhi(r.y);
  u[4] = bflo(r.z); u[5] = bfhi(r.z);
  u[6] = bflo(r.w); u[7] = bfhi(r.w);
}

// ---------- K1'': fused einsum + iter-0 chunk sums, scalar-path x ----------
// u_hat[b][i][od] = sum_n W[i,od,n] * x[b,i,n]  (bf16 out), AND
// part0[b][chunk][od] = sum_{i in chunk of 16} u_hat (fp32 accum, bf16 out).
// Eliminates the old k_sum0 full 128-MB re-read of u_hat.
// x is read at WAVE-UNIFORM addresses straight from global (2 MB, L2-hot):
// hipcc's uniformity analysis emits s_load -> SMEM pipe, freeing the LDS
// pipe entirely (the old xs-broadcast ds_read_b128 stream was ~41 us/CU of
// LDS issue — the suspected 2x over K1's 40 us streaming roofline).
// grid = 64 chunks * 8 od-slices = 512 blocks (2/CU); thread owns one od.
// acc[] fully unrolled over b -> static indices, stays in VGPRs.
__global__ __launch_bounds__(256) void k_einsum_sum(const float* __restrict__ x,
                                                    const float* __restrict__ W,
                                                    uint16_t* __restrict__ uhat,
                                                    uint16_t* __restrict__ part0) {
  const int chunk = blockIdx.x >> 3;     // 0..63
  const int q     = blockIdx.x & 7;      // od slice
  const int t     = threadIdx.x;
  const int od    = q * 256 + t;
  const int i0    = chunk * 16;
  float acc[B_];
  #pragma unroll
  for (int bb = 0; bb < B_; ++bb) acc[bb] = 0.f;
  for (int ii = 0; ii < 16; ++ii) {      // i-loop rolled (keeps I-cache small)
    const int i = i0 + ii;
    float w[16];
    {
      const float4* Wp = (const float4*)(W + (size_t)i * (OD_ * N_) + (size_t)od * N_);
      #pragma unroll
      for (int qq = 0; qq < 4; ++qq) {
        float4 f = Wp[qq];
        w[qq * 4 + 0] = f.x; w[qq * 4 + 1] = f.y;
        w[qq * 4 + 2] = f.z; w[qq * 4 + 3] = f.w;
      }
    }
    uint16_t* ub = uhat + (size_t)i * OD_ + od;     // + bb*(I_*OD_) per b
    const float* xi = x + (size_t)i * N_;           // + bb*(I_*N_) per b (uniform)
    #pragma unroll
    for (int bb = 0; bb < B_; ++bb) {
      const float* xb = xi + (size_t)bb * (I_ * N_);  // wave-uniform -> scalar loads
      float a = 0.f;
      #pragma unroll
      for (int n = 0; n < 16; ++n) a = fmaf(w[n], xb[n], a);
      ub[(size_t)bb * (I_ * OD_)] = (uint16_t)f2bf1(a);
      acc[bb] += a;                       // fp32 pre-rounding accumulation
    }
  }
  #pragma unroll
  for (int bb = 0; bb < B_; ++bb)
    part0[((size_t)bb * NCH0 + chunk) * OD_ + od] = (uint16_t)f2bf1(acc[bb]);
}

// ---------- squash: reduce NCH bf16 chunk-partials, scale, (+bias), squash over d ----------
template <int NCH>
__global__ __launch_bounds__(256) void k_squash(const uint16_t* __restrict__ part,
                                                const float* __restrict__ bias,
                                                float* __restrict__ vout,
                                                float scale, int addBias) {
  const int lane = threadIdx.x & 63;
  const int row = blockIdx.x * 4 + (threadIdx.x >> 6);  // b=row>>6, o=row&63
  const int b = row >> 6, o = row & 63;
  const int d = lane & 31;
  const uint16_t* p = part + (size_t)b * (NCH * OD_) + (size_t)o * 32 + d;
  float s = 0.f;
  const int c0 = (lane >> 5) * (NCH / 2);   // half-waves split the chunks
  #pragma unroll
  for (int c = 0; c < NCH / 2; ++c)
    s += __uint_as_float(((uint32_t)p[(size_t)(c0 + c) * OD_]) << 16);
  s += __shfl_xor(s, 32);
  s *= scale;
  if (addBias) s += bias[o * 32 + d];
  float dot = s * s;
  #pragma unroll
  for (int off = 1; off <= 16; off <<= 1) dot += __shfl_xor(dot, off);
  float sc = dot / (1.f + dot) / sqrtf(dot + 1e-8f);
  if (lane < 32) vout[(size_t)row * 32 + d] = s * sc;
}

// ---------- routing pass (iters 1 and 2), lane = o, minimal registers ----------
// (frozen — unchanged from the 297-µs known-good version)
__global__ __launch_bounds__(256) void k_route(const uint4* __restrict__ uhat,
                                               const float* __restrict__ vprev,
                                               float* __restrict__ bij,
                                               uint4* __restrict__ part,
                                               int secondIter) {
  const int b = blockIdx.x >> 5, chunk = blockIdx.x & 31;
  const int t = threadIdx.x;
  const int w = t >> 6, lane = t & 63;   // lane = o
  __shared__ float red[4][64][32];       // 32 KB, swizzled [w][o][(d+o)&31]
  uint32_t vp[16];
  {
    const float4* vpt = (const float4*)(vprev + ((size_t)b * 64 + lane) * 32);
    #pragma unroll
    for (int q = 0; q < 8; ++q) {
      float4 f = vpt[q];
      vp[2 * q]     = pack2(f.x, f.y);
      vp[2 * q + 1] = pack2(f.z, f.w);
    }
  }
  float s_acc[32];
  #pragma unroll
  for (int d = 0; d < 32; ++d) s_acc[d] = 0.f;
  const int i0 = chunk * 32 + w * 8;
  const uint4* ub = uhat + ((size_t)b * I_ + i0) * 256 + (size_t)lane * 4;
  for (int r = 0; r < 8; ++r) {
    const uint4* uc = ub + (size_t)r * 256;
    uint4 c0 = uc[0], c1 = uc[1], c2 = uc[2], c3 = uc[3];
    float a = 0.f;
    {
      float u8[8];
      unpack8(c0, u8);
      #pragma unroll
      for (int p = 0; p < 4; ++p) {
        uint32_t vv = vp[p];
        a = fmaf(u8[2 * p], bflo(vv), a);
        a = fmaf(u8[2 * p + 1], bfhi(vv), a);
      }
      unpack8(c1, u8);
      #pragma unroll
      for (int p = 0; p < 4; ++p) {
        uint32_t vv = vp[4 + p];
        a = fmaf(u8[2 * p], bflo(vv), a);
        a = fmaf(u8[2 * p + 1], bfhi(vv), a);
      }
      unpack8(c2, u8);
      #pragma unroll
      for (int p = 0; p < 4; ++p) {
        uint32_t vv = vp[8 + p];
        a = fmaf(u8[2 * p], bflo(vv), a);
        a = fmaf(u8[2 * p + 1], bfhi(vv), a);
      }
      unpack8(c3, u8);
      #pragma unroll
      for (int p = 0; p < 4; ++p) {
        uint32_t vv = vp[12 + p];
        a = fmaf(u8[2 * p], bflo(vv), a);
        a = fmaf(u8[2 * p + 1], bfhi(vv), a);
      }
    }
    const int i = i0 + r;
    const size_t bidx = ((size_t)b * I_ + i) * 64 + lane;
    float bn = a;
    if (secondIter) bn += bij[bidx];
    else            bij[bidx] = bn;
    float m = bn;
    #pragma unroll
    for (int off = 1; off <= 32; off <<= 1) m = fmaxf(m, __shfl_xor(m, off));
    float e = __expf(bn - m);
    float sm = e;
    #pragma unroll
    for (int off = 1; off <= 32; off <<= 1) sm += __shfl_xor(sm, off);
    const float c = e / sm;
    {
      float u8[8];
      unpack8(c0, u8);
      #pragma unroll
      for (int j = 0; j < 8; ++j) s_acc[j] = fmaf(c, u8[j], s_acc[j]);
      unpack8(c1, u8);
      #pragma unroll
      for (int j = 0; j < 8; ++j) s_acc[8 + j] = fmaf(c, u8[j], s_acc[8 + j]);
      unpack8(c2, u8);
      #pragma unroll
      for (int j = 0; j < 8; ++j) s_acc[16 + j] = fmaf(c, u8[j], s_acc[16 + j]);
      unpack8(c3, u8);
      #pragma unroll
      for (int j = 0; j < 8; ++j) s_acc[24 + j] = fmaf(c, u8[j], s_acc[24 + j]);
    }
  }
  #pragma unroll
  for (int d = 0; d < 32; ++d) red[w][lane][(d + lane) & 31] = s_acc[d];
  __syncthreads();
  {
    const int o = t >> 2, db = (t & 3) * 8;
    float sum[8];
    #pragma unroll
    for (int j = 0; j < 8; ++j) {
      const int sw = (db + j + o) & 31;
      sum[j] = red[0][o][sw] + red[1][o][sw] + red[2][o][sw] + red[3][o][sw];
    }
    part[(((size_t)b * 32 + chunk) * OD_ + (size_t)t * 8) >> 3] =
        make_uint4(pack2(sum[0], sum[1]), pack2(sum[2], sum[3]),
                   pack2(sum[4], sum[5]), pack2(sum[6], sum[7]));
  }
}

extern "C" void kernel_launch(void* const* d_in, const int* in_sizes, int n_in,
                              void* d_out, int out_size, void* d_ws, size_t ws_size,
                              hipStream_t stream) {
  const float* x    = (const float*)d_in[0];  // [32,1024,16]
  const float* W    = (const float*)d_in[1];  // [1,1024,64,32,16]
  const float* bias = (const float*)d_in[2];  // [1,1,64,32]
  float* out = (float*)d_out;                 // [32,64,32]

  char* ws = (char*)d_ws;
  // Workspace layout (140.25 MiB total — identical footprint to the proven 297-µs version):
  //   [0,128M)       uhat   bf16 u_hat[b][i][od]
  //   [128,136M)     part0  bf16 iter-0 partials [b][64][od]  (dead after squash0)
  //   [128,136M)     bij    fp32 b_ij[b,i,o]   (aliases part0; written in route1, AFTER part0 dead)
  //   [136,140M)     rpart  bf16 route partials [b][32][od]
  //   [140M,+256K)   vbuf   fp32 v[b,od]
  uint16_t* uhat1 = (uint16_t*)ws;
  uint4*    uhat4 = (uint4*)ws;
  uint16_t* part0 = (uint16_t*)(ws + 134217728ull);
  float*    bij   = (float*)   (ws + 134217728ull);
  uint4*    rpart = (uint4*)   (ws + 134217728ull + 8388608ull);
  uint16_t* rpart16 = (uint16_t*)rpart;
  float*    vbuf  = (float*)   (ws + 134217728ull + 8388608ull + 4194304ull);

  // fused einsum + iter-0 uniform sum (c = 1/64 applied in squash scale)
  k_einsum_sum<<<dim3(512), dim3(256), 0, stream>>>(x, W, uhat1, part0);
  k_squash<NCH0><<<dim3(512), dim3(256), 0, stream>>>(part0, bias, vbuf, 1.f / 64.f, 0);
  // iter 1
  k_route<<<dim3(1024), dim3(256), 0, stream>>>(uhat4, vbuf, bij, rpart, 0);
  k_squash<32><<<dim3(512), dim3(256), 0, stream>>>(rpart16, bias, vbuf, 1.f, 0);
  // iter 2 (last): + bias, output
  k_route<<<dim3(1024), dim3(256), 0, stream>>>(uhat4, vbuf, bij, rpart, 1);
  k_squash<32><<<dim3(512), dim3(256), 0, stream>>>(rpart16, bias, out, 1.f, 1);
}

// Round 6
// 370.322 us; speedup vs baseline: 1.1634x; 1.1634x over previous
//
#include <hip/hip_runtime.h>
#include <hip/hip_bf16.h>
#include <stdint.h>

// Problem constants (FC_Caps): B=32, I=1024, O=64, D_out=32, D_in=16
#define B_   32
#define I_   1024
#define O_   64
#define D_   32
#define N_   16
#define OD_  2048   // O_*D_
#define NCH0 64     // iter-0 chunk count (16 i per chunk) — keeps ws at proven 140.25 MiB

// ---------- bf16 helpers (bit-exact RNE pack, shift unpack) ----------
__device__ __forceinline__ uint32_t f2bf1(float f) {
  uint32_t u = __float_as_uint(f);
  return (u + 0x7fffu + ((u >> 16) & 1u)) >> 16;
}
__device__ __forceinline__ uint32_t pack2(float a, float b) {
  return f2bf1(a) | (f2bf1(b) << 16);
}
__device__ __forceinline__ float bflo(uint32_t v) { return __uint_as_float(v << 16); }
__device__ __forceinline__ float bfhi(uint32_t v) { return __uint_as_float(v & 0xffff0000u); }
__device__ __forceinline__ void unpack8(uint4 r, float* u) {
  u[0] = bflo(r.x); u[1] = bfhi(r.x);
  u[2] = bflo(r.y); u[3] = bfhi(r.y);
  u[4] = bflo(r.z); u[5] = bfhi(r.z);
  u[6] = bflo(r.w); u[7] = bfhi(r.w);
}

// ---------- K1v3: fused einsum + iter-0 chunk sums, old-K1 LDS-broadcast inner ----------
// POST-MORTEM R3: scalar-path x (s_load) was latency-bound — 230 us, VALUBusy 29%,
// occ 23%: SMEM chain per bb can't pipeline (112 SGPR), 8 waves/CU can't hide it.
// Back to the PROVEN old-K1 inner pattern (85 us): 2 od rows/thread, float4
// LDS-broadcast x reads, identical FMA order -> identical u_hat numerics.
// New grid keeps the part0 fusion: block = (chunk 16 i) x (od-quarter 512) x
// (bb-octet 8). Grid 64*4*4 = 1024 blocks, 4/CU, 16 waves/CU.
// bb-octet is the FASTEST blockIdx digit: the 4 siblings sharing a W slice are
// adjacent in dispatch -> co-resident -> L3 absorbs the x4 W re-read.
__global__ __launch_bounds__(256) void k_einsum_sum(const float* __restrict__ x,
                                                    const float* __restrict__ W,
                                                    uint16_t* __restrict__ uhat,
                                                    uint16_t* __restrict__ part0) {
  const int bx      = blockIdx.x;
  const int chunk   = bx >> 4;        // 0..63
  const int quarter = (bx >> 2) & 3;  // 0..3  (512 od each)
  const int bbs     = bx & 3;         // 0..3  (8 b each)
  const int t       = threadIdx.x;
  const int od0     = quarter * 512 + t;   // row A; row B = od0 + 256
  const int i0      = chunk * 16;
  const int b0      = bbs * 8;
  __shared__ float xs[16 * 8 * 16];   // [ii][bb][n] = 8 KB
  for (int idx = t; idx < 512; idx += 256) {          // 512 float4 loads
    const int bb = idx >> 6, rem = idx & 63;          // rem = ii*4 + n4
    const int ii = rem >> 2, n4 = rem & 3;
    float4 f = *(const float4*)(x + (size_t)(b0 + bb) * (I_ * N_) +
                                (size_t)(i0 + ii) * N_ + n4 * 4);
    *(float4*)(xs + ii * 128 + bb * 16 + n4 * 4) = f;
  }
  __syncthreads();
  float accA[8], accB[8];
  #pragma unroll
  for (int bb = 0; bb < 8; ++bb) { accA[bb] = 0.f; accB[bb] = 0.f; }
  for (int ii = 0; ii < 16; ++ii) {   // i-loop rolled (keeps I-cache small)
    const int i = i0 + ii;
    float wA[16], wB[16];
    {
      const float4* Wa = (const float4*)(W + (size_t)i * (OD_ * N_) + (size_t)od0 * N_);
      const float4* Wb = (const float4*)(W + (size_t)i * (OD_ * N_) + (size_t)(od0 + 256) * N_);
      #pragma unroll
      for (int qq = 0; qq < 4; ++qq) {
        float4 fa = Wa[qq];
        wA[qq * 4 + 0] = fa.x; wA[qq * 4 + 1] = fa.y;
        wA[qq * 4 + 2] = fa.z; wA[qq * 4 + 3] = fa.w;
        float4 fb = Wb[qq];
        wB[qq * 4 + 0] = fb.x; wB[qq * 4 + 1] = fb.y;
        wB[qq * 4 + 2] = fb.z; wB[qq * 4 + 3] = fb.w;
      }
    }
    #pragma unroll
    for (int bb = 0; bb < 8; ++bb) {
      const float4* xp = (const float4*)(xs + ii * 128 + bb * 16);  // wave-uniform broadcast
      float4 x0 = xp[0], x1 = xp[1], x2 = xp[2], x3 = xp[3];
      float xv[16] = {x0.x, x0.y, x0.z, x0.w, x1.x, x1.y, x1.z, x1.w,
                      x2.x, x2.y, x2.z, x2.w, x3.x, x3.y, x3.z, x3.w};
      float a0 = 0.f, a1 = 0.f;
      #pragma unroll
      for (int n = 0; n < 16; ++n) {
        a0 = fmaf(wA[n], xv[n], a0);
        a1 = fmaf(wB[n], xv[n], a1);
      }
      const size_t base = ((size_t)(b0 + bb) * I_ + i) * OD_ + od0;
      uhat[base]       = (uint16_t)f2bf1(a0);
      uhat[base + 256] = (uint16_t)f2bf1(a1);
      accA[bb] += a0;                 // fp32 pre-rounding accumulation
      accB[bb] += a1;
    }
  }
  #pragma unroll
  for (int bb = 0; bb < 8; ++bb) {
    const size_t pb = ((size_t)(b0 + bb) * NCH0 + chunk) * OD_ + od0;
    part0[pb]       = (uint16_t)f2bf1(accA[bb]);
    part0[pb + 256] = (uint16_t)f2bf1(accB[bb]);
  }
}

// ---------- squash: reduce NCH bf16 chunk-partials, scale, (+bias), squash over d ----------
template <int NCH>
__global__ __launch_bounds__(256) void k_squash(const uint16_t* __restrict__ part,
                                                const float* __restrict__ bias,
                                                float* __restrict__ vout,
                                                float scale, int addBias) {
  const int lane = threadIdx.x & 63;
  const int row = blockIdx.x * 4 + (threadIdx.x >> 6);  // b=row>>6, o=row&63
  const int b = row >> 6, o = row & 63;
  const int d = lane & 31;
  const uint16_t* p = part + (size_t)b * (NCH * OD_) + (size_t)o * 32 + d;
  float s = 0.f;
  const int c0 = (lane >> 5) * (NCH / 2);   // half-waves split the chunks
  #pragma unroll
  for (int c = 0; c < NCH / 2; ++c)
    s += __uint_as_float(((uint32_t)p[(size_t)(c0 + c) * OD_]) << 16);
  s += __shfl_xor(s, 32);
  s *= scale;
  if (addBias) s += bias[o * 32 + d];
  float dot = s * s;
  #pragma unroll
  for (int off = 1; off <= 16; off <<= 1) dot += __shfl_xor(dot, off);
  float sc = dot / (1.f + dot) / sqrtf(dot + 1e-8f);
  if (lane < 32) vout[(size_t)row * 32 + d] = s * sc;
}

// ---------- routing pass (iters 1 and 2), lane = o, minimal registers ----------
// (frozen — unchanged from the 297-µs known-good version)
__global__ __launch_bounds__(256) void k_route(const uint4* __restrict__ uhat,
                                               const float* __restrict__ vprev,
                                               float* __restrict__ bij,
                                               uint4* __restrict__ part,
                                               int secondIter) {
  const int b = blockIdx.x >> 5, chunk = blockIdx.x & 31;
  const int t = threadIdx.x;
  const int w = t >> 6, lane = t & 63;   // lane = o
  __shared__ float red[4][64][32];       // 32 KB, swizzled [w][o][(d+o)&31]
  uint32_t vp[16];
  {
    const float4* vpt = (const float4*)(vprev + ((size_t)b * 64 + lane) * 32);
    #pragma unroll
    for (int q = 0; q < 8; ++q) {
      float4 f = vpt[q];
      vp[2 * q]     = pack2(f.x, f.y);
      vp[2 * q + 1] = pack2(f.z, f.w);
    }
  }
  float s_acc[32];
  #pragma unroll
  for (int d = 0; d < 32; ++d) s_acc[d] = 0.f;
  const int i0 = chunk * 32 + w * 8;
  const uint4* ub = uhat + ((size_t)b * I_ + i0) * 256 + (size_t)lane * 4;
  for (int r = 0; r < 8; ++r) {
    const uint4* uc = ub + (size_t)r * 256;
    uint4 c0 = uc[0], c1 = uc[1], c2 = uc[2], c3 = uc[3];
    float a = 0.f;
    {
      float u8[8];
      unpack8(c0, u8);
      #pragma unroll
      for (int p = 0; p < 4; ++p) {
        uint32_t vv = vp[p];
        a = fmaf(u8[2 * p], bflo(vv), a);
        a = fmaf(u8[2 * p + 1], bfhi(vv), a);
      }
      unpack8(c1, u8);
      #pragma unroll
      for (int p = 0; p < 4; ++p) {
        uint32_t vv = vp[4 + p];
        a = fmaf(u8[2 * p], bflo(vv), a);
        a = fmaf(u8[2 * p + 1], bfhi(vv), a);
      }
      unpack8(c2, u8);
      #pragma unroll
      for (int p = 0; p < 4; ++p) {
        uint32_t vv = vp[8 + p];
        a = fmaf(u8[2 * p], bflo(vv), a);
        a = fmaf(u8[2 * p + 1], bfhi(vv), a);
      }
      unpack8(c3, u8);
      #pragma unroll
      for (int p = 0; p < 4; ++p) {
        uint32_t vv = vp[12 + p];
        a = fmaf(u8[2 * p], bflo(vv), a);
        a = fmaf(u8[2 * p + 1], bfhi(vv), a);
      }
    }
    const int i = i0 + r;
    const size_t bidx = ((size_t)b * I_ + i) * 64 + lane;
    float bn = a;
    if (secondIter) bn += bij[bidx];
    else            bij[bidx] = bn;
    float m = bn;
    #pragma unroll
    for (int off = 1; off <= 32; off <<= 1) m = fmaxf(m, __shfl_xor(m, off));
    float e = __expf(bn - m);
    float sm = e;
    #pragma unroll
    for (int off = 1; off <= 32; off <<= 1) sm += __shfl_xor(sm, off);
    const float c = e / sm;
    {
      float u8[8];
      unpack8(c0, u8);
      #pragma unroll
      for (int j = 0; j < 8; ++j) s_acc[j] = fmaf(c, u8[j], s_acc[j]);
      unpack8(c1, u8);
      #pragma unroll
      for (int j = 0; j < 8; ++j) s_acc[8 + j] = fmaf(c, u8[j], s_acc[8 + j]);
      unpack8(c2, u8);
      #pragma unroll
      for (int j = 0; j < 8; ++j) s_acc[16 + j] = fmaf(c, u8[j], s_acc[16 + j]);
      unpack8(c3, u8);
      #pragma unroll
      for (int j = 0; j < 8; ++j) s_acc[24 + j] = fmaf(c, u8[j], s_acc[24 + j]);
    }
  }
  #pragma unroll
  for (int d = 0; d < 32; ++d) red[w][lane][(d + lane) & 31] = s_acc[d];
  __syncthreads();
  {
    const int o = t >> 2, db = (t & 3) * 8;
    float sum[8];
    #pragma unroll
    for (int j = 0; j < 8; ++j) {
      const int sw = (db + j + o) & 31;
      sum[j] = red[0][o][sw] + red[1][o][sw] + red[2][o][sw] + red[3][o][sw];
    }
    part[(((size_t)b * 32 + chunk) * OD_ + (size_t)t * 8) >> 3] =
        make_uint4(pack2(sum[0], sum[1]), pack2(sum[2], sum[3]),
                   pack2(sum[4], sum[5]), pack2(sum[6], sum[7]));
  }
}

extern "C" void kernel_launch(void* const* d_in, const int* in_sizes, int n_in,
                              void* d_out, int out_size, void* d_ws, size_t ws_size,
                              hipStream_t stream) {
  const float* x    = (const float*)d_in[0];  // [32,1024,16]
  const float* W    = (const float*)d_in[1];  // [1,1024,64,32,16]
  const float* bias = (const float*)d_in[2];  // [1,1,64,32]
  float* out = (float*)d_out;                 // [32,64,32]

  char* ws = (char*)d_ws;
  // Workspace layout (140.25 MiB total — identical footprint to the proven 297-µs version):
  //   [0,128M)       uhat   bf16 u_hat[b][i][od]
  //   [128,136M)     part0  bf16 iter-0 partials [b][64][od]  (dead after squash0)
  //   [128,136M)     bij    fp32 b_ij[b,i,o]   (aliases part0; written in route1, AFTER part0 dead)
  //   [136,140M)     rpart  bf16 route partials [b][32][od]
  //   [140M,+256K)   vbuf   fp32 v[b,od]
  uint16_t* uhat1 = (uint16_t*)ws;
  uint4*    uhat4 = (uint4*)ws;
  uint16_t* part0 = (uint16_t*)(ws + 134217728ull);
  float*    bij   = (float*)   (ws + 134217728ull);
  uint4*    rpart = (uint4*)   (ws + 134217728ull + 8388608ull);
  uint16_t* rpart16 = (uint16_t*)rpart;
  float*    vbuf  = (float*)   (ws + 134217728ull + 8388608ull + 4194304ull);

  // fused einsum + iter-0 uniform sum (c = 1/64 applied in squash scale)
  k_einsum_sum<<<dim3(1024), dim3(256), 0, stream>>>(x, W, uhat1, part0);
  k_squash<NCH0><<<dim3(512), dim3(256), 0, stream>>>(part0, bias, vbuf, 1.f / 64.f, 0);
  // iter 1
  k_route<<<dim3(1024), dim3(256), 0, stream>>>(uhat4, vbuf, bij, rpart, 0);
  k_squash<32><<<dim3(512), dim3(256), 0, stream>>>(rpart16, bias, vbuf, 1.f, 0);
  // iter 2 (last): + bias, output
  k_route<<<dim3(1024), dim3(256), 0, stream>>>(uhat4, vbuf, bij, rpart, 1);
  k_squash<32><<<dim3(512), dim3(256), 0, stream>>>(rpart16, bias, out, 1.f, 1);
}

// Round 7
// 334.319 us; speedup vs baseline: 1.2887x; 1.1077x over previous
//
#include <hip/hip_runtime.h>
#include <hip/hip_bf16.h>
#include <stdint.h>

// Problem constants (FC_Caps): B=32, I=1024, O=64, D_out=32, D_in=16
#define B_   32
#define I_   1024
#define O_   64
#define D_   32
#define N_   16
#define OD_  2048   // O_*D_
#define NCH0 64     // iter-0 chunk count (16 i per chunk) — keeps ws at proven 140.25 MiB

// ---------- bf16 helpers (bit-exact RNE pack, shift unpack) ----------
__device__ __forceinline__ uint32_t f2bf1(float f) {
  uint32_t u = __float_as_uint(f);
  return (u + 0x7fffu + ((u >> 16) & 1u)) >> 16;
}
__device__ __forceinline__ uint32_t pack2(float a, float b) {
  return f2bf1(a) | (f2bf1(b) << 16);
}
__device__ __forceinline__ float bflo(uint32_t v) { return __uint_as_float(v << 16); }
__device__ __forceinline__ float bfhi(uint32_t v) { return __uint_as_float(v & 0xffff0000u); }
__device__ __forceinline__ void unpack8(uint4 r, float* u) {
  u[0] = bflo(r.x); u[1] = bfhi(r.x);
  u[2] = bflo(r.y); u[3] = bfhi(r.y);
  u[4] = bflo(r.z); u[5] = bfhi(r.z);
  u[6] = bflo(r.w); u[7] = bfhi(r.w);
}

// ---------- K1v4: fused einsum + iter-0 chunk sums, XCD-co-located siblings ----------
// POST-MORTEM R5: K1v3 = 170 us, FETCH 376 MB = ~3x W. The 4 bb-octet siblings
// sharing a 2 MB W slice were CONSECUTIVE blockIdx -> round-robin onto 4
// DIFFERENT XCDs -> concurrent same-line misses in 4 private L2s do NOT merge
// at L3 -> W fetched ~3x from HBM. Fix: remap so siblings share one XCD
// (dispatch heuristic XCD = blockIdx % 8; locality-only, correctness-safe).
// Same-XCD concurrent misses merge in that L2's MSHRs; skewed re-reads hit L2/L3.
// Work per block / LDS pattern / FMA order byte-identical to K1v3.
__global__ __launch_bounds__(256) void k_einsum_sum(const float* __restrict__ x,
                                                    const float* __restrict__ W,
                                                    uint16_t* __restrict__ uhat,
                                                    uint16_t* __restrict__ part0) {
  const int bx      = blockIdx.x;
  const int xcd     = bx & 7;         // XCD under round-robin dispatch
  const int k       = bx >> 3;        // 0..127: this XCD's dispatch sequence
  const int bbs     = k & 3;          // sibling index — same-XCD adjacent
  const int g       = (xcd << 5) | (k >> 2);  // 0..255 W-slice group
  const int chunk   = g >> 2;         // 0..63
  const int quarter = g & 3;          // 0..3  (512 od each)
  const int t       = threadIdx.x;
  const int od0     = quarter * 512 + t;   // row A; row B = od0 + 256
  const int i0      = chunk * 16;
  const int b0      = bbs * 8;
  __shared__ float xs[16 * 8 * 16];   // [ii][bb][n] = 8 KB
  for (int idx = t; idx < 512; idx += 256) {          // 512 float4 loads
    const int bb = idx >> 6, rem = idx & 63;          // rem = ii*4 + n4
    const int ii = rem >> 2, n4 = rem & 3;
    float4 f = *(const float4*)(x + (size_t)(b0 + bb) * (I_ * N_) +
                                (size_t)(i0 + ii) * N_ + n4 * 4);
    *(float4*)(xs + ii * 128 + bb * 16 + n4 * 4) = f;
  }
  __syncthreads();
  float accA[8], accB[8];
  #pragma unroll
  for (int bb = 0; bb < 8; ++bb) { accA[bb] = 0.f; accB[bb] = 0.f; }
  for (int ii = 0; ii < 16; ++ii) {   // i-loop rolled (keeps I-cache small)
    const int i = i0 + ii;
    float wA[16], wB[16];
    {
      const float4* Wa = (const float4*)(W + (size_t)i * (OD_ * N_) + (size_t)od0 * N_);
      const float4* Wb = (const float4*)(W + (size_t)i * (OD_ * N_) + (size_t)(od0 + 256) * N_);
      #pragma unroll
      for (int qq = 0; qq < 4; ++qq) {
        float4 fa = Wa[qq];
        wA[qq * 4 + 0] = fa.x; wA[qq * 4 + 1] = fa.y;
        wA[qq * 4 + 2] = fa.z; wA[qq * 4 + 3] = fa.w;
        float4 fb = Wb[qq];
        wB[qq * 4 + 0] = fb.x; wB[qq * 4 + 1] = fb.y;
        wB[qq * 4 + 2] = fb.z; wB[qq * 4 + 3] = fb.w;
      }
    }
    #pragma unroll
    for (int bb = 0; bb < 8; ++bb) {
      const float4* xp = (const float4*)(xs + ii * 128 + bb * 16);  // wave-uniform broadcast
      float4 x0 = xp[0], x1 = xp[1], x2 = xp[2], x3 = xp[3];
      float xv[16] = {x0.x, x0.y, x0.z, x0.w, x1.x, x1.y, x1.z, x1.w,
                      x2.x, x2.y, x2.z, x2.w, x3.x, x3.y, x3.z, x3.w};
      float a0 = 0.f, a1 = 0.f;
      #pragma unroll
      for (int n = 0; n < 16; ++n) {
        a0 = fmaf(wA[n], xv[n], a0);
        a1 = fmaf(wB[n], xv[n], a1);
      }
      const size_t base = ((size_t)(b0 + bb) * I_ + i) * OD_ + od0;
      uhat[base]       = (uint16_t)f2bf1(a0);
      uhat[base + 256] = (uint16_t)f2bf1(a1);
      accA[bb] += a0;                 // fp32 pre-rounding accumulation
      accB[bb] += a1;
    }
  }
  #pragma unroll
  for (int bb = 0; bb < 8; ++bb) {
    const size_t pb = ((size_t)(b0 + bb) * NCH0 + chunk) * OD_ + od0;
    part0[pb]       = (uint16_t)f2bf1(accA[bb]);
    part0[pb + 256] = (uint16_t)f2bf1(accB[bb]);
  }
}

// ---------- squash: reduce NCH bf16 chunk-partials, scale, (+bias), squash over d ----------
template <int NCH>
__global__ __launch_bounds__(256) void k_squash(const uint16_t* __restrict__ part,
                                                const float* __restrict__ bias,
                                                float* __restrict__ vout,
                                                float scale, int addBias) {
  const int lane = threadIdx.x & 63;
  const int row = blockIdx.x * 4 + (threadIdx.x >> 6);  // b=row>>6, o=row&63
  const int b = row >> 6, o = row & 63;
  const int d = lane & 31;
  const uint16_t* p = part + (size_t)b * (NCH * OD_) + (size_t)o * 32 + d;
  float s = 0.f;
  const int c0 = (lane >> 5) * (NCH / 2);   // half-waves split the chunks
  #pragma unroll
  for (int c = 0; c < NCH / 2; ++c)
    s += __uint_as_float(((uint32_t)p[(size_t)(c0 + c) * OD_]) << 16);
  s += __shfl_xor(s, 32);
  s *= scale;
  if (addBias) s += bias[o * 32 + d];
  float dot = s * s;
  #pragma unroll
  for (int off = 1; off <= 16; off <<= 1) dot += __shfl_xor(dot, off);
  float sc = dot / (1.f + dot) / sqrtf(dot + 1e-8f);
  if (lane < 32) vout[(size_t)row * 32 + d] = s * sc;
}

// ---------- routing pass (iters 1 and 2), lane = o, minimal registers ----------
// (frozen — unchanged from the 297-µs known-good version)
__global__ __launch_bounds__(256) void k_route(const uint4* __restrict__ uhat,
                                               const float* __restrict__ vprev,
                                               float* __restrict__ bij,
                                               uint4* __restrict__ part,
                                               int secondIter) {
  const int b = blockIdx.x >> 5, chunk = blockIdx.x & 31;
  const int t = threadIdx.x;
  const int w = t >> 6, lane = t & 63;   // lane = o
  __shared__ float red[4][64][32];       // 32 KB, swizzled [w][o][(d+o)&31]
  uint32_t vp[16];
  {
    const float4* vpt = (const float4*)(vprev + ((size_t)b * 64 + lane) * 32);
    #pragma unroll
    for (int q = 0; q < 8; ++q) {
      float4 f = vpt[q];
      vp[2 * q]     = pack2(f.x, f.y);
      vp[2 * q + 1] = pack2(f.z, f.w);
    }
  }
  float s_acc[32];
  #pragma unroll
  for (int d = 0; d < 32; ++d) s_acc[d] = 0.f;
  const int i0 = chunk * 32 + w * 8;
  const uint4* ub = uhat + ((size_t)b * I_ + i0) * 256 + (size_t)lane * 4;
  for (int r = 0; r < 8; ++r) {
    const uint4* uc = ub + (size_t)r * 256;
    uint4 c0 = uc[0], c1 = uc[1], c2 = uc[2], c3 = uc[3];
    float a = 0.f;
    {
      float u8[8];
      unpack8(c0, u8);
      #pragma unroll
      for (int p = 0; p < 4; ++p) {
        uint32_t vv = vp[p];
        a = fmaf(u8[2 * p], bflo(vv), a);
        a = fmaf(u8[2 * p + 1], bfhi(vv), a);
      }
      unpack8(c1, u8);
      #pragma unroll
      for (int p = 0; p < 4; ++p) {
        uint32_t vv = vp[4 + p];
        a = fmaf(u8[2 * p], bflo(vv), a);
        a = fmaf(u8[2 * p + 1], bfhi(vv), a);
      }
      unpack8(c2, u8);
      #pragma unroll
      for (int p = 0; p < 4; ++p) {
        uint32_t vv = vp[8 + p];
        a = fmaf(u8[2 * p], bflo(vv), a);
        a = fmaf(u8[2 * p + 1], bfhi(vv), a);
      }
      unpack8(c3, u8);
      #pragma unroll
      for (int p = 0; p < 4; ++p) {
        uint32_t vv = vp[12 + p];
        a = fmaf(u8[2 * p], bflo(vv), a);
        a = fmaf(u8[2 * p + 1], bfhi(vv), a);
      }
    }
    const int i = i0 + r;
    const size_t bidx = ((size_t)b * I_ + i) * 64 + lane;
    float bn = a;
    if (secondIter) bn += bij[bidx];
    else            bij[bidx] = bn;
    float m = bn;
    #pragma unroll
    for (int off = 1; off <= 32; off <<= 1) m = fmaxf(m, __shfl_xor(m, off));
    float e = __expf(bn - m);
    float sm = e;
    #pragma unroll
    for (int off = 1; off <= 32; off <<= 1) sm += __shfl_xor(sm, off);
    const float c = e / sm;
    {
      float u8[8];
      unpack8(c0, u8);
      #pragma unroll
      for (int j = 0; j < 8; ++j) s_acc[j] = fmaf(c, u8[j], s_acc[j]);
      unpack8(c1, u8);
      #pragma unroll
      for (int j = 0; j < 8; ++j) s_acc[8 + j] = fmaf(c, u8[j], s_acc[8 + j]);
      unpack8(c2, u8);
      #pragma unroll
      for (int j = 0; j < 8; ++j) s_acc[16 + j] = fmaf(c, u8[j], s_acc[16 + j]);
      unpack8(c3, u8);
      #pragma unroll
      for (int j = 0; j < 8; ++j) s_acc[24 + j] = fmaf(c, u8[j], s_acc[24 + j]);
    }
  }
  #pragma unroll
  for (int d = 0; d < 32; ++d) red[w][lane][(d + lane) & 31] = s_acc[d];
  __syncthreads();
  {
    const int o = t >> 2, db = (t & 3) * 8;
    float sum[8];
    #pragma unroll
    for (int j = 0; j < 8; ++j) {
      const int sw = (db + j + o) & 31;
      sum[j] = red[0][o][sw] + red[1][o][sw] + red[2][o][sw] + red[3][o][sw];
    }
    part[(((size_t)b * 32 + chunk) * OD_ + (size_t)t * 8) >> 3] =
        make_uint4(pack2(sum[0], sum[1]), pack2(sum[2], sum[3]),
                   pack2(sum[4], sum[5]), pack2(sum[6], sum[7]));
  }
}

extern "C" void kernel_launch(void* const* d_in, const int* in_sizes, int n_in,
                              void* d_out, int out_size, void* d_ws, size_t ws_size,
                              hipStream_t stream) {
  const float* x    = (const float*)d_in[0];  // [32,1024,16]
  const float* W    = (const float*)d_in[1];  // [1,1024,64,32,16]
  const float* bias = (const float*)d_in[2];  // [1,1,64,32]
  float* out = (float*)d_out;                 // [32,64,32]

  char* ws = (char*)d_ws;
  // Workspace layout (140.25 MiB total — identical footprint to the proven 297-µs version):
  //   [0,128M)       uhat   bf16 u_hat[b][i][od]
  //   [128,136M)     part0  bf16 iter-0 partials [b][64][od]  (dead after squash0)
  //   [128,136M)     bij    fp32 b_ij[b,i,o]   (aliases part0; written in route1, AFTER part0 dead)
  //   [136,140M)     rpart  bf16 route partials [b][32][od]
  //   [140M,+256K)   vbuf   fp32 v[b,od]
  uint16_t* uhat1 = (uint16_t*)ws;
  uint4*    uhat4 = (uint4*)ws;
  uint16_t* part0 = (uint16_t*)(ws + 134217728ull);
  float*    bij   = (float*)   (ws + 134217728ull);
  uint4*    rpart = (uint4*)   (ws + 134217728ull + 8388608ull);
  uint16_t* rpart16 = (uint16_t*)rpart;
  float*    vbuf  = (float*)   (ws + 134217728ull + 8388608ull + 4194304ull);

  // fused einsum + iter-0 uniform sum (c = 1/64 applied in squash scale)
  k_einsum_sum<<<dim3(1024), dim3(256), 0, stream>>>(x, W, uhat1, part0);
  k_squash<NCH0><<<dim3(512), dim3(256), 0, stream>>>(part0, bias, vbuf, 1.f / 64.f, 0);
  // iter 1
  k_route<<<dim3(1024), dim3(256), 0, stream>>>(uhat4, vbuf, bij, rpart, 0);
  k_squash<32><<<dim3(512), dim3(256), 0, stream>>>(rpart16, bias, vbuf, 1.f, 0);
  // iter 2 (last): + bias, output
  k_route<<<dim3(1024), dim3(256), 0, stream>>>(uhat4, vbuf, bij, rpart, 1);
  k_squash<32><<<dim3(512), dim3(256), 0, stream>>>(rpart16, bias, out, 1.f, 1);
}